// Round 9
// baseline (525.089 us; speedup 1.0000x reference)
//
#include <hip/hip_runtime.h>
#include <hip/hip_bf16.h>
#include <stdint.h>

#define NE   64
#define DIM  1024
#define HID  512
#define TPE  1024   // tokens per expert (uniform in this problem)

typedef __attribute__((ext_vector_type(8)))  __bf16          bf16x8;
typedef __attribute__((ext_vector_type(4)))  float           f32x4;
typedef __attribute__((ext_vector_type(8)))  unsigned short  ushort8_t;
typedef __attribute__((ext_vector_type(4)))  unsigned short  ushort4_t;
typedef __attribute__((ext_vector_type(4)))  float           float4_t;

__device__ __forceinline__ unsigned short f2bf(float f) {
  return __builtin_bit_cast(unsigned short, static_cast<__bf16>(f));  // RNE
}
__device__ __forceinline__ float bf2f(unsigned short u) {
  unsigned int x = ((unsigned int)u) << 16;
  return __builtin_bit_cast(float, x);
}
__device__ __forceinline__ ushort8_t pack8(float4_t a, float4_t b) {
  ushort8_t r;
  r[0] = f2bf(a[0]); r[1] = f2bf(a[1]); r[2] = f2bf(a[2]); r[3] = f2bf(a[3]);
  r[4] = f2bf(b[0]); r[5] = f2bf(b[1]); r[6] = f2bf(b[2]); r[7] = f2bf(b[3]);
  return r;
}
__device__ __forceinline__ bf16x8 ldsfrag(const unsigned short* p) {
  return __builtin_bit_cast(bf16x8, *reinterpret_cast<const ushort8_t*>(p));
}
__device__ __forceinline__ void barrier_lgkm() {
  asm volatile("s_waitcnt lgkmcnt(0)" ::: "memory");
  __builtin_amdgcn_s_barrier();
}
typedef __attribute__((address_space(1))) const unsigned int gas_uint;
typedef __attribute__((address_space(3))) unsigned int las_uint;
__device__ __forceinline__ void gload16(const void* g, void* l) {
  __builtin_amdgcn_global_load_lds((gas_uint*)g, (las_uint*)l, 16, 0, 0);
}

__device__ __forceinline__ int xcd_swizzle(int bid, int nwg) {
  return (bid & 7) * (nwg >> 3) + (bid >> 3);
}

// ===========================================================================
// conv_w: W1||W3 -> WB13 (stacked [e][g][256][1024] bf16), W2 -> W2b.
// Region per block (uniform, branch-free inner loop), 4 independent chunks
// in flight per iteration (ILP vs R8's 1-deep chain). 576 MB traffic.
// ===========================================================================
__global__ __launch_bounds__(256) void conv_w(
    const float* __restrict__ W1, const float* __restrict__ W3,
    const float* __restrict__ W2,
    unsigned short* __restrict__ WB13, unsigned short* __restrict__ W2b) {
  const int rb  = blockIdx.x;          // 0..1535: [0,512)=W1 [512,1024)=W3 [1024,1536)=W2
  const int reg = rb >> 9;
  const int rbl = rb & 511;
  const int f0  = rbl * 256 + threadIdx.x;   // region-local chunk id
  const int STRIDE = 512 * 256;              // 131072 chunks

  const float* src = (reg == 0) ? W1 : (reg == 1) ? W3 : W2;

#pragma unroll 1
  for (int it = 0; it < 8; ++it) {
    float4_t v[4][2];
    int f[4];
#pragma unroll
    for (int u = 0; u < 4; ++u) {
      f[u] = f0 + (it * 4 + u) * STRIDE;
      const float* p = src + (size_t)f[u] * 8;
      v[u][0] = *reinterpret_cast<const float4_t*>(p);
      v[u][1] = *reinterpret_cast<const float4_t*>(p + 4);
    }
#pragma unroll
    for (int u = 0; u < 4; ++u) {
      size_t dst;
      if (reg == 2) {
        dst = (size_t)f[u] * 8;                       // W2 straight copy
        *reinterpret_cast<ushort8_t*>(W2b + dst) = pack8(v[u][0], v[u][1]);
      } else {
        const int e  = f[u] >> 16;                    // 65536 chunks/expert
        const int h  = (f[u] >> 7) & 511;             // source row in [0,512)
        const int c8 = f[u] & 127;
        const int g  = h >> 7, r = (h & 127) + (reg == 1 ? 128 : 0);
        dst = ((((size_t)(e * 4 + g)) * 256 + r) * 128 + c8) * 8;
        *reinterpret_cast<ushort8_t*>(WB13 + dst) = pack8(v[u][0], v[u][1]);
      }
    }
  }
}

// ===========================================================================
// GEMM core (p2 / B-side shared idiom): tile 256x256, BK=64, 8 waves (2Mx4N).
// LDS [2buf][A|B][256*64] bf16 = 128 KiB. XOR swizzle: granule c16 ^ (row&7);
// gload_lds source pre-swizzled, reads apply the same XOR (involution).
// 4 phases/K-tile; vmcnt(0)+lgkmcnt(0)+barrier once per K-tile (loads get a
// full tile ~1000cy of flight); setprio(1) around MFMA cluster.
// ===========================================================================
#define GEMM_IDS                                                               \
  const int lane = threadIdx.x & 63;                                           \
  const int wid  = threadIdx.x >> 6;                                           \
  const int wr   = wid >> 2, wn = wid & 3;                                     \
  const int fr   = lane & 15;                                                  \
  const int c16b = lane >> 4;                                                  \
  const int swz  = fr & 7;                                                     \
  const int s_r  = lane >> 3;                                                  \
  const int s_c  = ((lane & 7) ^ s_r) * 8;

#define GEMM_ACC_INIT                                                          \
  f32x4 acc[8][4];                                                             \
  _Pragma("unroll") for (int m = 0; m < 8; ++m)                                \
    _Pragma("unroll") for (int n = 0; n < 4; ++n)                              \
      _Pragma("unroll") for (int i = 0; i < 4; ++i) acc[m][n][i] = 0.f;

#define RD_FRAGS(buf, kk)                                                      \
  bf16x8 af[8], bf0, bf1;                                                      \
  (void)0

// ---------------------------------------------------------------------------
// p1: H = bf16( silu(X@W1^T) * (X@W3^T) ).
// A = X fp32, REG-STAGED (T14 issue-early/write-late): 8 float4 loads at tile
// top -> pack8 + swizzled ds_write_b128 AFTER the last MFMA phase; published
// by the tile-boundary lgkmcnt(0)+barrier. B = WB13 bf16 via gload_lds
// (1 per phase). B-tile = [128 W1-rows ; 128 W3-rows] (stacked): wn<2 waves
// hold W1 results, wn>=2 the matching W3; epilogue exchanges via LDS.
// ---------------------------------------------------------------------------
__global__ __launch_bounds__(512, 2) void p1_fast(
    const float* __restrict__ X, const unsigned short* __restrict__ WB13,
    unsigned short* __restrict__ H) {
  __shared__ __align__(16) unsigned short smem[2][2][256 * 64];  // 128 KiB

  const int tile = xcd_swizzle(blockIdx.x, NE * 4 * 4);
  const int e  = tile >> 4;
  const int tm = (tile >> 2) & 3;    // token tile of 256
  const int g  = tile & 3;           // inner: X fp32 slab (1 MB) stays L2-hot
  const float*          gA = X    + (size_t)(e * TPE + tm * 256) * DIM;
  const unsigned short* gB = WB13 + (size_t)(e * 4 + g) * 256 * DIM;

  GEMM_IDS
  GEMM_ACC_INIT

  // A reg-stage mapping: thread -> (row = t>>1, half = t&1 of 32 fp32)
  const int arow = threadIdx.x >> 1, ah = threadIdx.x & 1;
  float4_t fa[8];

  auto loadA = [&](int kt) {
    const float* p = gA + (size_t)arow * DIM + kt * 64 + ah * 32;
#pragma unroll
    for (int j = 0; j < 8; ++j)
      fa[j] = *reinterpret_cast<const float4_t*>(p + j * 4);
  };
  auto writeA = [&](int buf) {
    const int base = arow * 64;
#pragma unroll
    for (int j = 0; j < 4; ++j) {
      const int gidx = (ah * 4 + j) ^ (arow & 7);
      *reinterpret_cast<ushort8_t*>(&smem[buf][0][base + gidx * 8]) =
          pack8(fa[2 * j], fa[2 * j + 1]);
    }
  };
  auto stB = [&](int buf, int kt, int j) {
    gload16(gB + (size_t)(j * 8 + s_r) * DIM + kt * 64 + s_c,
            &smem[buf][1][j * 512]);
  };
  auto rdA = [&](int buf, int m, int kk) {
    const int row = wr * 128 + m * 16 + fr;
    return ldsfrag(&smem[buf][0][row * 64 + (((c16b + kk * 4) ^ swz) * 8)]);
  };
  auto rdB = [&](int buf, int nf, int kk) {
    const int row = wn * 64 + nf * 16 + fr;
    return ldsfrag(&smem[buf][1][row * 64 + (((c16b + kk * 4) ^ swz) * 8)]);
  };

  // prologue: tile 0 -> buf 0
  loadA(0);
#pragma unroll 1
  for (int j = 0; j < 4; ++j) stB(0, 0, wid * 4 + j);
  writeA(0);                                // counted vmcnt: waits A loads only

  for (int kt = 0; kt < 16; ++kt) {
    const int buf = kt & 1, sbuf = buf ^ 1;
    const bool st = (kt + 1 < 16);
    asm volatile("s_waitcnt vmcnt(0) lgkmcnt(0)" ::: "memory");
    __builtin_amdgcn_s_barrier();           // buf ready (B drained, A published)
    asm volatile("" ::: "memory");
    if (st) loadA(kt + 1);                  // full-tile flight
    bf16x8 af[8];
#pragma unroll
    for (int q = 0; q < 4; ++q) {
      const int kk = q >> 1, nh = q & 1;
      if (nh == 0) {
#pragma unroll
        for (int m = 0; m < 8; ++m) af[m] = rdA(buf, m, kk);
      }
      bf16x8 bf0 = rdB(buf, nh * 2 + 0, kk);
      bf16x8 bf1 = rdB(buf, nh * 2 + 1, kk);
      if (st) stB(sbuf, kt + 1, wid * 4 + q);
      asm volatile("" ::: "memory");
      __builtin_amdgcn_s_barrier();
      __builtin_amdgcn_s_setprio(1);
#pragma unroll
      for (int m = 0; m < 8; ++m) {
        acc[m][nh * 2 + 0] = __builtin_amdgcn_mfma_f32_16x16x32_bf16(
            af[m], bf0, acc[m][nh * 2 + 0], 0, 0, 0);
        acc[m][nh * 2 + 1] = __builtin_amdgcn_mfma_f32_16x16x32_bf16(
            af[m], bf1, acc[m][nh * 2 + 1], 0, 0, 0);
      }
      __builtin_amdgcn_s_setprio(0);
    }
    if (st) writeA(sbuf);                   // late write; published next tile
  }

  // epilogue: exchange W3 half via LDS, combine in W1 waves.
  __builtin_amdgcn_s_barrier();
  unsigned short* bex = &smem[0][0][0];     // [128 hid][264 tok]
  const int q4 = (lane >> 4) * 4;
  if (wn >= 2) {
#pragma unroll
    for (int m = 0; m < 8; ++m)
#pragma unroll
      for (int n = 0; n < 4; ++n) {
        const int hidl = (wn - 2) * 64 + n * 16 + fr;
        const int tokl = wr * 128 + m * 16 + q4;
        ushort4_t v;
#pragma unroll
        for (int r = 0; r < 4; ++r) v[r] = f2bf(acc[m][n][r]);
        *reinterpret_cast<ushort4_t*>(&bex[hidl * 264 + tokl]) = v;
      }
  }
  barrier_lgkm();
  if (wn < 2) {
    const int rowbase = e * TPE + tm * 256;
#pragma unroll
    for (int m = 0; m < 8; ++m)
#pragma unroll
      for (int n = 0; n < 4; ++n) {
        const int hidl = wn * 64 + n * 16 + fr;
        const int tokl = wr * 128 + m * 16 + q4;
        const ushort4_t bv =
            *reinterpret_cast<const ushort4_t*>(&bex[hidl * 264 + tokl]);
#pragma unroll
        for (int r = 0; r < 4; ++r) {
          const float av = bf2f(f2bf(acc[m][n][r]));   // ref bf16 rounding
          const float b  = bf2f(bv[r]);
          const float s  = av / (1.0f + __expf(-av));
          H[(size_t)(rowbase + tokl + r) * HID + g * 128 + hidl] = f2bf(s * b);
        }
      }
  }
}

// ---------------------------------------------------------------------------
// p2: OUT = fp32( bf16( H @ W2b^T ) ). Both operands bf16 via gload_lds.
// ---------------------------------------------------------------------------
__global__ __launch_bounds__(512, 2) void p2_fast(
    const unsigned short* __restrict__ Hb, const unsigned short* __restrict__ W2b,
    float* __restrict__ OUT) {
  __shared__ __align__(16) unsigned short smem[2][2][256 * 64];  // 128 KiB

  const int tile = xcd_swizzle(blockIdx.x, NE * 4 * 4);
  const int e  = tile >> 4;
  const int tn = (tile >> 2) & 3;
  const int tm = tile & 3;           // inner: W2b slab L2-hot
  const unsigned short* gA = Hb  + (size_t)(e * TPE + tm * 256) * HID;
  const unsigned short* gB = W2b + (size_t)(e * DIM + tn * 256) * HID;

  GEMM_IDS
  GEMM_ACC_INIT

  auto stA = [&](int buf, int kt, int j) {
    gload16(gA + (size_t)(j * 8 + s_r) * HID + kt * 64 + s_c,
            &smem[buf][0][j * 512]);
  };
  auto stB = [&](int buf, int kt, int j) {
    gload16(gB + (size_t)(j * 8 + s_r) * HID + kt * 64 + s_c,
            &smem[buf][1][j * 512]);
  };
  auto rdA = [&](int buf, int m, int kk) {
    const int row = wr * 128 + m * 16 + fr;
    return ldsfrag(&smem[buf][0][row * 64 + (((c16b + kk * 4) ^ swz) * 8)]);
  };
  auto rdB = [&](int buf, int nf, int kk) {
    const int row = wn * 64 + nf * 16 + fr;
    return ldsfrag(&smem[buf][1][row * 64 + (((c16b + kk * 4) ^ swz) * 8)]);
  };

#pragma unroll 1
  for (int j = 0; j < 4; ++j) stA(0, 0, wid * 4 + j);
#pragma unroll 1
  for (int j = 0; j < 4; ++j) stB(0, 0, wid * 4 + j);

  for (int kt = 0; kt < 8; ++kt) {
    const int buf = kt & 1, sbuf = buf ^ 1;
    const bool st = (kt + 1 < 8);
    asm volatile("s_waitcnt vmcnt(0) lgkmcnt(0)" ::: "memory");
    __builtin_amdgcn_s_barrier();
    asm volatile("" ::: "memory");
    bf16x8 af[8];
#pragma unroll
    for (int q = 0; q < 4; ++q) {
      const int kk = q >> 1, nh = q & 1;
      if (nh == 0) {
#pragma unroll
        for (int m = 0; m < 8; ++m) af[m] = rdA(buf, m, kk);
      }
      bf16x8 bf0 = rdB(buf, nh * 2 + 0, kk);
      bf16x8 bf1 = rdB(buf, nh * 2 + 1, kk);
      if (st) {
        if (q < 2) { stA(sbuf, kt + 1, wid * 4 + q * 2);
                     stA(sbuf, kt + 1, wid * 4 + q * 2 + 1); }
        else       { stB(sbuf, kt + 1, wid * 4 + (q - 2) * 2);
                     stB(sbuf, kt + 1, wid * 4 + (q - 2) * 2 + 1); }
      }
      asm volatile("" ::: "memory");
      __builtin_amdgcn_s_barrier();
      __builtin_amdgcn_s_setprio(1);
#pragma unroll
      for (int m = 0; m < 8; ++m) {
        acc[m][nh * 2 + 0] = __builtin_amdgcn_mfma_f32_16x16x32_bf16(
            af[m], bf0, acc[m][nh * 2 + 0], 0, 0, 0);
        acc[m][nh * 2 + 1] = __builtin_amdgcn_mfma_f32_16x16x32_bf16(
            af[m], bf1, acc[m][nh * 2 + 1], 0, 0, 0);
      }
      __builtin_amdgcn_s_setprio(0);
    }
  }

  const int q4 = (lane >> 4) * 4;
  const int rowbase = e * TPE + tm * 256;
#pragma unroll
  for (int m = 0; m < 8; ++m)
#pragma unroll
    for (int n = 0; n < 4; ++n) {
      const int d    = tn * 256 + wn * 64 + n * 16 + fr;
      const int tokl = wr * 128 + m * 16 + q4;
#pragma unroll
      for (int r = 0; r < 4; ++r)
        OUT[(size_t)(rowbase + tokl + r) * DIM + d] = bf2f(f2bf(acc[m][n][r]));
    }
}

// ---------------------------------------------------------------------------
extern "C" void kernel_launch(void* const* d_in, const int* in_sizes, int n_in,
                              void* d_out, int out_size, void* d_ws, size_t ws_size,
                              hipStream_t stream) {
  (void)in_sizes; (void)n_in; (void)out_size; (void)ws_size;
  const float* X  = (const float*)d_in[0];
  const float* W1 = (const float*)d_in[1];
  const float* W2 = (const float*)d_in[2];
  const float* W3 = (const float*)d_in[3];
  float* OUT = (float*)d_out;

  // ws layout (needs 256 MiB; harness provides >=384 MiB — proven in R8):
  const size_t MiB = 1024 * 1024;
  unsigned short* WB13 = (unsigned short*)d_ws;                  // 128 MiB
  unsigned short* W2b  = WB13 + (size_t)128 * MiB / 2;           //  64 MiB
  unsigned short* H    = WB13 + (size_t)192 * MiB / 2;           //  64 MiB

  conv_w<<<dim3(1536), dim3(256), 0, stream>>>(W1, W3, W2, WB13, W2b);
  p1_fast<<<dim3(NE * 4 * 4), dim3(512), 0, stream>>>(X, WB13, H);
  p2_fast<<<dim3(NE * 4 * 4), dim3(512), 0, stream>>>(H, W2b, OUT);
}

// Round 10
// 454.402 us; speedup vs baseline: 1.1556x; 1.1556x over previous
//
#include <hip/hip_runtime.h>
#include <hip/hip_bf16.h>
#include <stdint.h>

#define NE   64
#define DIM  1024
#define HID  512
#define TPE  1024   // tokens per expert (uniform in this problem)

typedef __attribute__((ext_vector_type(8)))  __bf16          bf16x8;
typedef __attribute__((ext_vector_type(4)))  float           f32x4;
typedef __attribute__((ext_vector_type(8)))  unsigned short  ushort8_t;
typedef __attribute__((ext_vector_type(4)))  unsigned short  ushort4_t;
typedef __attribute__((ext_vector_type(4)))  float           float4_t;

__device__ __forceinline__ unsigned short f2bf(float f) {
  return __builtin_bit_cast(unsigned short, static_cast<__bf16>(f));  // RNE
}
__device__ __forceinline__ float bf2f(unsigned short u) {
  unsigned int x = ((unsigned int)u) << 16;
  return __builtin_bit_cast(float, x);
}
__device__ __forceinline__ ushort8_t pack8(float4_t a, float4_t b) {
  ushort8_t r;
  r[0] = f2bf(a[0]); r[1] = f2bf(a[1]); r[2] = f2bf(a[2]); r[3] = f2bf(a[3]);
  r[4] = f2bf(b[0]); r[5] = f2bf(b[1]); r[6] = f2bf(b[2]); r[7] = f2bf(b[3]);
  return r;
}
__device__ __forceinline__ bf16x8 ldsfrag(const unsigned short* p) {
  return __builtin_bit_cast(bf16x8, *reinterpret_cast<const ushort8_t*>(p));
}
__device__ __forceinline__ void barrier_lgkm() {
  asm volatile("s_waitcnt lgkmcnt(0)" ::: "memory");
  __builtin_amdgcn_s_barrier();
}
typedef __attribute__((address_space(1))) const unsigned int gas_uint;
typedef __attribute__((address_space(3))) unsigned int las_uint;
__device__ __forceinline__ void gload16(const void* g, void* l) {
  __builtin_amdgcn_global_load_lds((gas_uint*)g, (las_uint*)l, 16, 0, 0);
}

__device__ __forceinline__ int xcd_swizzle(int bid, int nwg) {
  return (bid & 7) * (nwg >> 3) + (bid >> 3);
}

// ===========================================================================
// conv_w: W1||W3 -> WB13 (stacked [e][g][256][1024] bf16), W2 -> W2b.
// Region per block, 4 independent chunks in flight (ILP). 576 MB traffic.
// ===========================================================================
__global__ __launch_bounds__(256) void conv_w(
    const float* __restrict__ W1, const float* __restrict__ W3,
    const float* __restrict__ W2,
    unsigned short* __restrict__ WB13, unsigned short* __restrict__ W2b) {
  const int rb  = blockIdx.x;          // [0,512)=W1 [512,1024)=W3 [1024,1536)=W2
  const int reg = rb >> 9;
  const int rbl = rb & 511;
  const int f0  = rbl * 256 + threadIdx.x;
  const int STRIDE = 512 * 256;

  const float* src = (reg == 0) ? W1 : (reg == 1) ? W3 : W2;

#pragma unroll 1
  for (int it = 0; it < 8; ++it) {
    float4_t v[4][2];
    int f[4];
#pragma unroll
    for (int u = 0; u < 4; ++u) {
      f[u] = f0 + (it * 4 + u) * STRIDE;
      const float* p = src + (size_t)f[u] * 8;
      v[u][0] = *reinterpret_cast<const float4_t*>(p);
      v[u][1] = *reinterpret_cast<const float4_t*>(p + 4);
    }
#pragma unroll
    for (int u = 0; u < 4; ++u) {
      size_t dst;
      if (reg == 2) {
        dst = (size_t)f[u] * 8;
        *reinterpret_cast<ushort8_t*>(W2b + dst) = pack8(v[u][0], v[u][1]);
      } else {
        const int e  = f[u] >> 16;
        const int h  = (f[u] >> 7) & 511;
        const int c8 = f[u] & 127;
        const int g  = h >> 7, r = (h & 127) + (reg == 1 ? 128 : 0);
        dst = ((((size_t)(e * 4 + g)) * 256 + r) * 128 + c8) * 8;
        *reinterpret_cast<ushort8_t*>(WB13 + dst) = pack8(v[u][0], v[u][1]);
      }
    }
  }
}

// ===========================================================================
// GEMM core ids: tile 256x256, BK=64, 8 waves (2Mx4N). LDS 128 KiB dbuf.
// XOR swizzle on 16-B granules: g' = g ^ (row&7); gload_lds sources are
// pre-swizzled, reg-staged writes apply the same XOR (involution).
// ===========================================================================
#define GEMM_IDS                                                               \
  const int lane = threadIdx.x & 63;                                           \
  const int wid  = threadIdx.x >> 6;                                           \
  const int wr   = wid >> 2, wn = wid & 3;                                     \
  const int fr   = lane & 15;                                                  \
  const int c16b = lane >> 4;                                                  \
  const int swz  = fr & 7;                                                     \
  const int s_r  = lane >> 3;                                                  \
  const int s_c  = ((lane & 7) ^ s_r) * 8;

#define GEMM_ACC_INIT                                                          \
  f32x4 acc[8][4];                                                             \
  _Pragma("unroll") for (int m = 0; m < 8; ++m)                                \
    _Pragma("unroll") for (int n = 0; n < 4; ++n)                              \
      _Pragma("unroll") for (int i = 0; i < 4; ++i) acc[m][n][i] = 0.f;

// ---------------------------------------------------------------------------
// p1: H = bf16( silu(X@W1^T) * (X@W3^T) ).
// A = X fp32 reg-staged. R10 FIX vs R9: COALESCED loadA — instr j reads 4
// consecutive rows, lanes 0-15 cover one row's 256 B contiguously (~16
// segments/instr vs R9's 64 scattered 16-B islands). Writes ds_write_b64 at
// XOR-swizzled granule. Schedule unchanged: loadA at tile top (full-tile
// cover for tail writeA and next-top vmcnt(0)); B via gload_lds 1/phase.
// ---------------------------------------------------------------------------
__global__ __launch_bounds__(512, 2) void p1_fast(
    const float* __restrict__ X, const unsigned short* __restrict__ WB13,
    unsigned short* __restrict__ H) {
  __shared__ __align__(16) unsigned short smem[2][2][256 * 64];  // 128 KiB

  const int tile = xcd_swizzle(blockIdx.x, NE * 4 * 4);
  const int e  = tile >> 4;
  const int tm = (tile >> 2) & 3;
  const int g  = tile & 3;           // inner: X fp32 slab L2/L3-hot
  const float*          gA = X    + (size_t)(e * TPE + tm * 256) * DIM;
  const unsigned short* gB = WB13 + (size_t)(e * 4 + g) * 256 * DIM;

  GEMM_IDS
  GEMM_ACC_INIT

  // A map: instr j -> rows [wid*32 + j*4, +4); lane -> row += lane>>4,
  // fp32 granule g16 = lane&15 (16 B). Lanes 0-15 = 256 B contiguous.
  const int a_rl  = lane >> 4;
  const int a_g16 = lane & 15;
  float4_t fa[8];

  auto loadA = [&](int kt) {
#pragma unroll
    for (int j = 0; j < 8; ++j) {
      const int row = wid * 32 + j * 4 + a_rl;
      fa[j] = *reinterpret_cast<const float4_t*>(
          gA + (size_t)row * DIM + kt * 64 + a_g16 * 4);
    }
  };
  auto writeA = [&](int buf) {
#pragma unroll
    for (int j = 0; j < 8; ++j) {
      const int row = wid * 32 + j * 4 + a_rl;
      const int gr  = (a_g16 >> 1) ^ (row & 7);   // swizzled 16-B granule
      ushort4_t v;
      v[0] = f2bf(fa[j][0]); v[1] = f2bf(fa[j][1]);
      v[2] = f2bf(fa[j][2]); v[3] = f2bf(fa[j][3]);
      *reinterpret_cast<ushort4_t*>(
          &smem[buf][0][row * 64 + gr * 8 + (a_g16 & 1) * 4]) = v;
    }
  };
  auto stB = [&](int buf, int kt, int j) {
    gload16(gB + (size_t)(j * 8 + s_r) * DIM + kt * 64 + s_c,
            &smem[buf][1][j * 512]);
  };
  auto rdA = [&](int buf, int m, int kk) {
    const int row = wr * 128 + m * 16 + fr;
    return ldsfrag(&smem[buf][0][row * 64 + (((c16b + kk * 4) ^ swz) * 8)]);
  };
  auto rdB = [&](int buf, int nf, int kk) {
    const int row = wn * 64 + nf * 16 + fr;
    return ldsfrag(&smem[buf][1][row * 64 + (((c16b + kk * 4) ^ swz) * 8)]);
  };

  // prologue: tile 0 -> buf 0
  loadA(0);
#pragma unroll 1
  for (int j = 0; j < 4; ++j) stB(0, 0, wid * 4 + j);
  writeA(0);                                // counted vmcnt: waits A loads only

  for (int kt = 0; kt < 16; ++kt) {
    const int buf = kt & 1, sbuf = buf ^ 1;
    const bool st = (kt + 1 < 16);
    asm volatile("s_waitcnt vmcnt(0) lgkmcnt(0)" ::: "memory");
    __builtin_amdgcn_s_barrier();           // buf ready (B drained, A published)
    asm volatile("" ::: "memory");
    if (st) loadA(kt + 1);                  // full-tile flight
    bf16x8 af[8];
#pragma unroll
    for (int q = 0; q < 4; ++q) {
      const int kk = q >> 1, nh = q & 1;
      if (nh == 0) {
#pragma unroll
        for (int m = 0; m < 8; ++m) af[m] = rdA(buf, m, kk);
      }
      bf16x8 bf0 = rdB(buf, nh * 2 + 0, kk);
      bf16x8 bf1 = rdB(buf, nh * 2 + 1, kk);
      if (st) stB(sbuf, kt + 1, wid * 4 + q);
      asm volatile("" ::: "memory");
      __builtin_amdgcn_s_barrier();
      __builtin_amdgcn_s_setprio(1);
#pragma unroll
      for (int m = 0; m < 8; ++m) {
        acc[m][nh * 2 + 0] = __builtin_amdgcn_mfma_f32_16x16x32_bf16(
            af[m], bf0, acc[m][nh * 2 + 0], 0, 0, 0);
        acc[m][nh * 2 + 1] = __builtin_amdgcn_mfma_f32_16x16x32_bf16(
            af[m], bf1, acc[m][nh * 2 + 1], 0, 0, 0);
      }
      __builtin_amdgcn_s_setprio(0);
    }
    if (st) writeA(sbuf);                   // late write; 4-phase-old A loads
  }

  // epilogue: exchange W3 half via LDS, combine in W1 waves.
  __builtin_amdgcn_s_barrier();
  unsigned short* bex = &smem[0][0][0];     // [128 hid][264 tok]
  const int q4 = (lane >> 4) * 4;
  if (wn >= 2) {
#pragma unroll
    for (int m = 0; m < 8; ++m)
#pragma unroll
      for (int n = 0; n < 4; ++n) {
        const int hidl = (wn - 2) * 64 + n * 16 + fr;
        const int tokl = wr * 128 + m * 16 + q4;
        ushort4_t v;
#pragma unroll
        for (int r = 0; r < 4; ++r) v[r] = f2bf(acc[m][n][r]);
        *reinterpret_cast<ushort4_t*>(&bex[hidl * 264 + tokl]) = v;
      }
  }
  barrier_lgkm();
  if (wn < 2) {
    const int rowbase = e * TPE + tm * 256;
#pragma unroll
    for (int m = 0; m < 8; ++m)
#pragma unroll
      for (int n = 0; n < 4; ++n) {
        const int hidl = wn * 64 + n * 16 + fr;
        const int tokl = wr * 128 + m * 16 + q4;
        const ushort4_t bv =
            *reinterpret_cast<const ushort4_t*>(&bex[hidl * 264 + tokl]);
#pragma unroll
        for (int r = 0; r < 4; ++r) {
          const float av = bf2f(f2bf(acc[m][n][r]));   // ref bf16 rounding
          const float b  = bf2f(bv[r]);
          const float s  = av / (1.0f + __expf(-av));
          H[(size_t)(rowbase + tokl + r) * HID + g * 128 + hidl] = f2bf(s * b);
        }
      }
  }
}

// ---------------------------------------------------------------------------
// p2: OUT = fp32( bf16( H @ W2b^T ) ). Both operands bf16 via gload_lds.
// ---------------------------------------------------------------------------
__global__ __launch_bounds__(512, 2) void p2_fast(
    const unsigned short* __restrict__ Hb, const unsigned short* __restrict__ W2b,
    float* __restrict__ OUT) {
  __shared__ __align__(16) unsigned short smem[2][2][256 * 64];  // 128 KiB

  const int tile = xcd_swizzle(blockIdx.x, NE * 4 * 4);
  const int e  = tile >> 4;
  const int tn = (tile >> 2) & 3;
  const int tm = tile & 3;           // inner: W2b slab L2-hot
  const unsigned short* gA = Hb  + (size_t)(e * TPE + tm * 256) * HID;
  const unsigned short* gB = W2b + (size_t)(e * DIM + tn * 256) * HID;

  GEMM_IDS
  GEMM_ACC_INIT

  auto stA = [&](int buf, int kt, int j) {
    gload16(gA + (size_t)(j * 8 + s_r) * HID + kt * 64 + s_c,
            &smem[buf][0][j * 512]);
  };
  auto stB = [&](int buf, int kt, int j) {
    gload16(gB + (size_t)(j * 8 + s_r) * HID + kt * 64 + s_c,
            &smem[buf][1][j * 512]);
  };
  auto rdA = [&](int buf, int m, int kk) {
    const int row = wr * 128 + m * 16 + fr;
    return ldsfrag(&smem[buf][0][row * 64 + (((c16b + kk * 4) ^ swz) * 8)]);
  };
  auto rdB = [&](int buf, int nf, int kk) {
    const int row = wn * 64 + nf * 16 + fr;
    return ldsfrag(&smem[buf][1][row * 64 + (((c16b + kk * 4) ^ swz) * 8)]);
  };

#pragma unroll 1
  for (int j = 0; j < 4; ++j) stA(0, 0, wid * 4 + j);
#pragma unroll 1
  for (int j = 0; j < 4; ++j) stB(0, 0, wid * 4 + j);

  for (int kt = 0; kt < 8; ++kt) {
    const int buf = kt & 1, sbuf = buf ^ 1;
    const bool st = (kt + 1 < 8);
    asm volatile("s_waitcnt vmcnt(0) lgkmcnt(0)" ::: "memory");
    __builtin_amdgcn_s_barrier();
    asm volatile("" ::: "memory");
    bf16x8 af[8];
#pragma unroll
    for (int q = 0; q < 4; ++q) {
      const int kk = q >> 1, nh = q & 1;
      if (nh == 0) {
#pragma unroll
        for (int m = 0; m < 8; ++m) af[m] = rdA(buf, m, kk);
      }
      bf16x8 bf0 = rdB(buf, nh * 2 + 0, kk);
      bf16x8 bf1 = rdB(buf, nh * 2 + 1, kk);
      if (st) {
        if (q < 2) { stA(sbuf, kt + 1, wid * 4 + q * 2);
                     stA(sbuf, kt + 1, wid * 4 + q * 2 + 1); }
        else       { stB(sbuf, kt + 1, wid * 4 + (q - 2) * 2);
                     stB(sbuf, kt + 1, wid * 4 + (q - 2) * 2 + 1); }
      }
      asm volatile("" ::: "memory");
      __builtin_amdgcn_s_barrier();
      __builtin_amdgcn_s_setprio(1);
#pragma unroll
      for (int m = 0; m < 8; ++m) {
        acc[m][nh * 2 + 0] = __builtin_amdgcn_mfma_f32_16x16x32_bf16(
            af[m], bf0, acc[m][nh * 2 + 0], 0, 0, 0);
        acc[m][nh * 2 + 1] = __builtin_amdgcn_mfma_f32_16x16x32_bf16(
            af[m], bf1, acc[m][nh * 2 + 1], 0, 0, 0);
      }
      __builtin_amdgcn_s_setprio(0);
    }
  }

  const int q4 = (lane >> 4) * 4;
  const int rowbase = e * TPE + tm * 256;
#pragma unroll
  for (int m = 0; m < 8; ++m)
#pragma unroll
    for (int n = 0; n < 4; ++n) {
      const int d    = tn * 256 + wn * 64 + n * 16 + fr;
      const int tokl = wr * 128 + m * 16 + q4;
#pragma unroll
      for (int r = 0; r < 4; ++r)
        OUT[(size_t)(rowbase + tokl + r) * DIM + d] = bf2f(f2bf(acc[m][n][r]));
    }
}

// ---------------------------------------------------------------------------
extern "C" void kernel_launch(void* const* d_in, const int* in_sizes, int n_in,
                              void* d_out, int out_size, void* d_ws, size_t ws_size,
                              hipStream_t stream) {
  (void)in_sizes; (void)n_in; (void)out_size; (void)ws_size;
  const float* X  = (const float*)d_in[0];
  const float* W1 = (const float*)d_in[1];
  const float* W2 = (const float*)d_in[2];
  const float* W3 = (const float*)d_in[3];
  float* OUT = (float*)d_out;

  const size_t MiB = 1024 * 1024;
  unsigned short* WB13 = (unsigned short*)d_ws;                  // 128 MiB
  unsigned short* W2b  = WB13 + (size_t)128 * MiB / 2;           //  64 MiB
  unsigned short* H    = WB13 + (size_t)192 * MiB / 2;           //  64 MiB

  conv_w<<<dim3(1536), dim3(256), 0, stream>>>(W1, W3, W2, WB13, W2b);
  p1_fast<<<dim3(NE * 4 * 4), dim3(512), 0, stream>>>(X, WB13, H);
  p2_fast<<<dim3(NE * 4 * 4), dim3(512), 0, stream>>>(H, W2b, OUT);
}